// Round 1
// baseline (242.568 us; speedup 1.0000x reference)
//
#include <hip/hip_runtime.h>

typedef unsigned short u16;
typedef unsigned int   u32;
typedef __bf16 bf16x8 __attribute__((ext_vector_type(8)));
typedef float  f32x4  __attribute__((ext_vector_type(4)));

__device__ __forceinline__ u16 f2bf(float f) {
    u32 u = __builtin_bit_cast(u32, f);
    u32 r = u + 0x7fffu + ((u >> 16) & 1u);   // RNE
    return (u16)(r >> 16);
}

__device__ __forceinline__ void gload16(const void* g, void* lds) {
    __builtin_amdgcn_global_load_lds(
        (const __attribute__((address_space(1))) u32*)g,
        (__attribute__((address_space(3))) u32*)lds, 16, 0, 0);
}

__device__ __forceinline__ f32x4 mfma16(bf16x8 a, bf16x8 b, f32x4 c) {
    return __builtin_amdgcn_mfma_f32_16x16x32_bf16(a, b, c, 0, 0, 0);
}

// ---------------- fp32 -> bf16 convert ----------------
__global__ __launch_bounds__(256) void k_cvt(const float* __restrict__ src,
                                             u16* __restrict__ dst, int n4) {
    int i = blockIdx.x * 256 + threadIdx.x;
    if (i < n4) {
        float4 v = ((const float4*)src)[i];
        ushort4 o;
        o.x = f2bf(v.x); o.y = f2bf(v.y); o.z = f2bf(v.z); o.w = f2bf(v.w);
        ((ushort4*)dst)[i] = o;
    }
}

// ---------------- NT GEMM: C[m,n] = sum_k A[m,k]*B[n,k] + bias[n] ----------------
// 128x128 tile, BK=64, 4 waves (2x2), each wave 64x64 = 4x4 frags of 16x16x32.
template<bool SILU, bool OUT_BF16>
__global__ __launch_bounds__(256) void k_gemm(const u16* __restrict__ A,
                                              const u16* __restrict__ B,
                                              const float* __restrict__ bias,
                                              void* __restrict__ Cout,
                                              int M, int N, int K) {
    __shared__ __align__(16) u16 As[128 * 64];
    __shared__ __align__(16) u16 Bs[128 * 64];
    const int tid = threadIdx.x;
    const int w = tid >> 6, l = tid & 63;
    const int wm = w >> 1, wn = w & 1;
    const int lr = l & 15, lg = l >> 4;
    const int m0 = blockIdx.x * 128, n0 = blockIdx.y * 128;

    f32x4 acc[4][4];
#pragma unroll
    for (int i = 0; i < 4; ++i)
#pragma unroll
        for (int j = 0; j < 4; ++j) acc[i][j] = (f32x4){0.f, 0.f, 0.f, 0.f};

    const int nkt = K >> 6;
    for (int kt = 0; kt < nkt; ++kt) {
        __syncthreads();
#pragma unroll
        for (int it = 0; it < 4; ++it) {
            const int cbase = it * 256 + w * 64;     // chunk base (16B units), wave-uniform
            const int c = cbase + l;
            const int row = c >> 3, col = (c & 7) * 8;
            gload16(&A[(size_t)(m0 + row) * K + kt * 64 + col], &As[cbase * 8]);
            gload16(&B[(size_t)(n0 + row) * K + kt * 64 + col], &Bs[cbase * 8]);
        }
        __syncthreads();
#pragma unroll
        for (int s = 0; s < 2; ++s) {
            bf16x8 af[4], bq[4];
#pragma unroll
            for (int f = 0; f < 4; ++f) {
                af[f] = *(const bf16x8*)&As[(wm * 64 + f * 16 + lr) * 64 + s * 32 + lg * 8];
                bq[f] = *(const bf16x8*)&Bs[(wn * 64 + f * 16 + lr) * 64 + s * 32 + lg * 8];
            }
#pragma unroll
            for (int mf = 0; mf < 4; ++mf)
#pragma unroll
                for (int nf = 0; nf < 4; ++nf)
                    acc[mf][nf] = mfma16(af[mf], bq[nf], acc[mf][nf]);
        }
    }
    // epilogue: D col = lane&15, row = (lane>>4)*4 + reg   [verified mapping]
#pragma unroll
    for (int nf = 0; nf < 4; ++nf) {
        const int col = n0 + wn * 64 + nf * 16 + lr;
        const float bv = bias[col];
#pragma unroll
        for (int mf = 0; mf < 4; ++mf) {
#pragma unroll
            for (int r = 0; r < 4; ++r) {
                const int row = m0 + wm * 64 + mf * 16 + lg * 4 + r;
                float v = acc[mf][nf][r] + bv;
                if (SILU) v = v / (1.0f + __expf(-v));
                if (OUT_BF16) ((u16*)Cout)[(size_t)row * N + col] = f2bf(v);
                else          ((float*)Cout)[(size_t)row * N + col] = v;
            }
        }
    }
}

// ---------------- V transpose: vt[bh][d][n] = qkv[b, n, 2048 + h*64 + d] ----------------
__global__ __launch_bounds__(256) void k_vt(const u16* __restrict__ qkv,
                                            u16* __restrict__ vt) {
    __shared__ u16 tile[64][66];
    const int bh = blockIdx.y;
    const int b = bh >> 4, h = bh & 15;
    const int n0 = blockIdx.x * 64;
    const int tid = threadIdx.x;
#pragma unroll
    for (int it = 0; it < 16; ++it) {
        int idx = it * 256 + tid;
        int r = idx >> 6, c = idx & 63;
        tile[r][c] = qkv[(size_t)(b * 2048 + n0 + r) * 3072 + 2048 + h * 64 + c];
    }
    __syncthreads();
#pragma unroll
    for (int it = 0; it < 16; ++it) {
        int idx = it * 256 + tid;
        int d = idx >> 6, c = idx & 63;
        vt[(size_t)(bh * 64 + d) * 2048 + n0 + c] = tile[c][d];
    }
}

// ---------------- windowed flash attention ----------------
// Per block: 64 q-rows (4 waves x 16), one (b,h). KV tiles of 64.
// S^T = mfma(K, Q): D row = kv, D col = q (lane&15) -> softmax q-index lane-local.
__global__ __launch_bounds__(256) void k_attn(const u16* __restrict__ qkv,
                                              const u16* __restrict__ vt,
                                              u16* __restrict__ ao) {
    __shared__ __align__(16) u16 Ks[64 * 64];
    __shared__ __align__(16) u16 Vs[64 * 64];
    __shared__ __align__(16) u16 Pl[4][16 * 72];   // per-wave P, padded rows (144B)
    const int bh = blockIdx.y, b = bh >> 4, h = bh & 15;
    const int i0 = blockIdx.x * 64;
    const int tid = threadIdx.x, w = tid >> 6, l = tid & 63;
    const int lr = l & 15, lg = l >> 4;
    const float LOG2E = 1.4426950408889634f;

    // Q fragments (B operand), n-index = q = lane&15
    const size_t qbase = (size_t)(b * 2048 + i0 + w * 16 + lr) * 3072 + h * 64;
    const bf16x8 qf0 = *(const bf16x8*)&qkv[qbase + lg * 8];
    const bf16x8 qf1 = *(const bf16x8*)&qkv[qbase + 32 + lg * 8];

    f32x4 o[4];
#pragma unroll
    for (int f = 0; f < 4; ++f) o[f] = (f32x4){0.f, 0.f, 0.f, 0.f};
    float mrun = -1e30f, lrun = 0.f;
    const int qg = i0 + w * 16 + lr;          // q owned by this lane (softmax state)
    const int ntiles = min((int)blockIdx.x + 2, 32);

    for (int t = 0; t < ntiles; ++t) {
        const int j0 = t * 64;
        __syncthreads();
        // stage K and V^T tiles, XOR-swizzled via pre-swizzled global source (m173)
#pragma unroll
        for (int it = 0; it < 2; ++it) {
            const int cbase = it * 256 + w * 64;
            const int c = cbase + l;
            const int row = c >> 3, slot = c & 7;
            const int ss = slot ^ (row & 7);
            gload16(&qkv[(size_t)(b * 2048 + j0 + row) * 3072 + 1024 + h * 64 + ss * 8],
                    &Ks[cbase * 8]);
            gload16(&vt[(size_t)(bh * 64 + row) * 2048 + j0 + ss * 8], &Vs[cbase * 8]);
        }
        __syncthreads();

        // S^T = K x Q^T  (rows = kv, cols = q)
        f32x4 st[4];
#pragma unroll
        for (int f = 0; f < 4; ++f) st[f] = (f32x4){0.f, 0.f, 0.f, 0.f};
#pragma unroll
        for (int s = 0; s < 2; ++s) {
            const bf16x8 qf = s ? qf1 : qf0;
#pragma unroll
            for (int f = 0; f < 4; ++f) {
                const int row = f * 16 + lr;
                const int sw = ((s * 4 + lg) ^ (row & 7)) * 8;
                bf16x8 kf = *(const bf16x8*)&Ks[row * 64 + sw];
                st[f] = mfma16(kf, qf, st[f]);
            }
        }
        // scale + window mask + row max (kv = j0 + f*16 + lg*4 + r, q = lane&15)
        float pmax = -1e30f;
#pragma unroll
        for (int f = 0; f < 4; ++f) {
#pragma unroll
            for (int r = 0; r < 4; ++r) {
                const int kv = j0 + f * 16 + lg * 4 + r;
                float sv = st[f][r] * 0.125f;
                if (kv > qg + 63) sv = -1e30f;
                st[f][r] = sv;
                pmax = fmaxf(pmax, sv);
            }
        }
        pmax = fmaxf(pmax, __shfl_xor(pmax, 16));
        pmax = fmaxf(pmax, __shfl_xor(pmax, 32));
        const float mnew = fmaxf(mrun, pmax);
        const float sc = exp2f((mrun - mnew) * LOG2E);
        mrun = mnew;

        float rs = 0.f;
#pragma unroll
        for (int f = 0; f < 4; ++f) {
            float p0 = exp2f((st[f][0] - mnew) * LOG2E);
            float p1 = exp2f((st[f][1] - mnew) * LOG2E);
            float p2 = exp2f((st[f][2] - mnew) * LOG2E);
            float p3 = exp2f((st[f][3] - mnew) * LOG2E);
            rs += p0 + p1 + p2 + p3;
            ushort4 pw;
            pw.x = f2bf(p0); pw.y = f2bf(p1); pw.z = f2bf(p2); pw.w = f2bf(p3);
            *(ushort4*)&Pl[w][lr * 72 + f * 16 + lg * 4] = pw;   // P[q][kv] row-major
        }
        rs += __shfl_xor(rs, 16);
        rs += __shfl_xor(rs, 32);
        lrun = lrun * sc + rs;

        // rescale O (O rows q = lg*4 + r -> fetch per-row scale via shuffle)
        float scr[4];
#pragma unroll
        for (int r = 0; r < 4; ++r) scr[r] = __shfl(sc, lg * 4 + r);
#pragma unroll
        for (int f = 0; f < 4; ++f) {
            o[f][0] *= scr[0]; o[f][1] *= scr[1];
            o[f][2] *= scr[2]; o[f][3] *= scr[3];
        }
        // O += P x V  (A = P[q][kv], B = V^T[d][kv]; identical contiguous-8 k pattern)
#pragma unroll
        for (int s = 0; s < 2; ++s) {
            const bf16x8 pf = *(const bf16x8*)&Pl[w][lr * 72 + s * 32 + lg * 8];
#pragma unroll
            for (int f = 0; f < 4; ++f) {
                const int row = f * 16 + lr;
                const int sw = ((s * 4 + lg) ^ (row & 7)) * 8;
                bf16x8 vf = *(const bf16x8*)&Vs[row * 64 + sw];
                o[f] = mfma16(pf, vf, o[f]);
            }
        }
    }
    // epilogue: O row q = lg*4 + r, col d = f*16 + lr
    float li[4];
#pragma unroll
    for (int r = 0; r < 4; ++r) li[r] = 1.0f / __shfl(lrun, lg * 4 + r);
#pragma unroll
    for (int f = 0; f < 4; ++f) {
#pragma unroll
        for (int r = 0; r < 4; ++r) {
            const int row = b * 2048 + i0 + w * 16 + lg * 4 + r;
            ao[(size_t)row * 1024 + h * 64 + f * 16 + lr] = f2bf(o[f][r] * li[r]);
        }
    }
}

extern "C" void kernel_launch(void* const* d_in, const int* in_sizes, int n_in,
                              void* d_out, int out_size, void* d_ws, size_t ws_size,
                              hipStream_t stream) {
    const float* x  = (const float*)d_in[0];
    const float* W1 = (const float*)d_in[1];
    const float* b1 = (const float*)d_in[2];
    const float* W2 = (const float*)d_in[3];
    const float* b2 = (const float*)d_in[4];
    const float* Wg = (const float*)d_in[5];
    const float* bg = (const float*)d_in[6];
    const float* Wo = (const float*)d_in[7];
    const float* bo = (const float*)d_in[8];
    float* out = (float*)d_out;

    char* ws = (char*)d_ws;
    const size_t MB = 1024 * 1024;
    u16* x_bf   = (u16*)(ws + 0);        // 8 MB
    u16* w1_bf  = (u16*)(ws + 8  * MB);  // 2 MB
    u16* w2_bf  = (u16*)(ws + 10 * MB);  // 2 MB
    u16* wg_bf  = (u16*)(ws + 12 * MB);  // 6 MB
    u16* wo_bf  = (u16*)(ws + 18 * MB);  // 2 MB
    u16* h1_bf  = (u16*)(ws + 20 * MB);  // 8 MB
    u16* h_bf   = (u16*)(ws + 28 * MB);  // 8 MB
    u16* qkv_bf = (u16*)(ws + 36 * MB);  // 24 MB
    u16* vt_bf  = (u16*)(ws + 60 * MB);  // 8 MB
    u16* ao_bf  = (u16*)(ws + 68 * MB);  // 8 MB (total 76 MB)

    k_cvt<<<4096, 256, 0, stream>>>(x,  x_bf,  1048576);
    k_cvt<<<1024, 256, 0, stream>>>(W1, w1_bf, 262144);
    k_cvt<<<1024, 256, 0, stream>>>(W2, w2_bf, 262144);
    k_cvt<<<3072, 256, 0, stream>>>(Wg, wg_bf, 786432);
    k_cvt<<<1024, 256, 0, stream>>>(Wo, wo_bf, 262144);

    k_gemm<true,  true ><<<dim3(32, 8),  256, 0, stream>>>(x_bf,  w1_bf, b1, h1_bf,  4096, 1024, 1024);
    k_gemm<false, true ><<<dim3(32, 8),  256, 0, stream>>>(h1_bf, w2_bf, b2, h_bf,   4096, 1024, 1024);
    k_gemm<false, true ><<<dim3(32, 24), 256, 0, stream>>>(h_bf,  wg_bf, bg, qkv_bf, 4096, 3072, 1024);

    k_vt  <<<dim3(32, 32), 256, 0, stream>>>(qkv_bf, vt_bf);
    k_attn<<<dim3(32, 32), 256, 0, stream>>>(qkv_bf, vt_bf, ao_bf);

    k_gemm<false, false><<<dim3(32, 8), 256, 0, stream>>>(ao_bf, wo_bf, bo, out, 4096, 1024, 1024);
}

// Round 3
// 195.145 us; speedup vs baseline: 1.2430x; 1.2430x over previous
//
#include <hip/hip_runtime.h>

typedef unsigned short u16;
typedef unsigned int   u32;
typedef __bf16 bf16x8 __attribute__((ext_vector_type(8)));
typedef float  f32x4  __attribute__((ext_vector_type(4)));

__device__ __forceinline__ u16 f2bf(float f) {
    u32 u = __builtin_bit_cast(u32, f);
    u32 r = u + 0x7fffu + ((u >> 16) & 1u);   // RNE
    return (u16)(r >> 16);
}

__device__ __forceinline__ void gload16(const void* g, void* lds) {
    __builtin_amdgcn_global_load_lds(
        (const __attribute__((address_space(1))) u32*)g,
        (__attribute__((address_space(3))) u32*)lds, 16, 0, 0);
}

__device__ __forceinline__ f32x4 mfma16(bf16x8 a, bf16x8 b, f32x4 c) {
    return __builtin_amdgcn_mfma_f32_16x16x32_bf16(a, b, c, 0, 0, 0);
}

// ---------------- fp32 -> bf16 convert ----------------
__global__ __launch_bounds__(256) void k_cvt(const float* __restrict__ src,
                                             u16* __restrict__ dst, int n4) {
    int i = blockIdx.x * 256 + threadIdx.x;
    if (i < n4) {
        float4 v = ((const float4*)src)[i];
        ushort4 o;
        o.x = f2bf(v.x); o.y = f2bf(v.y); o.z = f2bf(v.z); o.w = f2bf(v.w);
        ((ushort4*)dst)[i] = o;
    }
}

// ---------------- NT GEMM: C[m,n] = sum_k A[m,k]*B[n,k] + bias[n] ----------------
// 128x128 tile, BK=64, 4 waves (2x2), each wave 64x64 = 4x4 frags of 16x16x32.
// Columns col < qcols get scaled by 0.125*log2(e) (pre-scale of attention Q).
template<bool SILU, bool OUT_BF16>
__global__ __launch_bounds__(256) void k_gemm(const u16* __restrict__ A,
                                              const u16* __restrict__ B,
                                              const float* __restrict__ bias,
                                              void* __restrict__ Cout,
                                              int M, int N, int K, int qcols) {
    __shared__ __align__(16) u16 As[128 * 64];
    __shared__ __align__(16) u16 Bs[128 * 64];
    const int tid = threadIdx.x;
    const int w = tid >> 6, l = tid & 63;
    const int wm = w >> 1, wn = w & 1;
    const int lr = l & 15, lg = l >> 4;
    const int m0 = blockIdx.x * 128, n0 = blockIdx.y * 128;

    f32x4 acc[4][4];
#pragma unroll
    for (int i = 0; i < 4; ++i)
#pragma unroll
        for (int j = 0; j < 4; ++j) acc[i][j] = (f32x4){0.f, 0.f, 0.f, 0.f};

    const int nkt = K >> 6;
    for (int kt = 0; kt < nkt; ++kt) {
        __syncthreads();
#pragma unroll
        for (int it = 0; it < 4; ++it) {
            const int cbase = it * 256 + w * 64;     // chunk base (16B units), wave-uniform
            const int c = cbase + l;
            const int row = c >> 3, col = (c & 7) * 8;
            gload16(&A[(size_t)(m0 + row) * K + kt * 64 + col], &As[cbase * 8]);
            gload16(&B[(size_t)(n0 + row) * K + kt * 64 + col], &Bs[cbase * 8]);
        }
        __syncthreads();
#pragma unroll
        for (int s = 0; s < 2; ++s) {
            bf16x8 af[4], bq[4];
#pragma unroll
            for (int f = 0; f < 4; ++f) {
                af[f] = *(const bf16x8*)&As[(wm * 64 + f * 16 + lr) * 64 + s * 32 + lg * 8];
                bq[f] = *(const bf16x8*)&Bs[(wn * 64 + f * 16 + lr) * 64 + s * 32 + lg * 8];
            }
#pragma unroll
            for (int mf = 0; mf < 4; ++mf)
#pragma unroll
                for (int nf = 0; nf < 4; ++nf)
                    acc[mf][nf] = mfma16(af[mf], bq[nf], acc[mf][nf]);
        }
    }
    // epilogue: D col = lane&15, row = (lane>>4)*4 + reg   [verified mapping]
#pragma unroll
    for (int nf = 0; nf < 4; ++nf) {
        const int col = n0 + wn * 64 + nf * 16 + lr;
        const float bv = bias[col];
        const float cs = (col < qcols) ? 0.18033688011112042f : 1.0f;
#pragma unroll
        for (int mf = 0; mf < 4; ++mf) {
#pragma unroll
            for (int r = 0; r < 4; ++r) {
                const int row = m0 + wm * 64 + mf * 16 + lg * 4 + r;
                float v = acc[mf][nf][r] + bv;
                if (SILU) v = v / (1.0f + __expf(-v));
                v *= cs;
                if (OUT_BF16) ((u16*)Cout)[(size_t)row * N + col] = f2bf(v);
                else          ((float*)Cout)[(size_t)row * N + col] = v;
            }
        }
    }
}

// ---------------- V transpose: vt[bh][d][n] = qkv[b, n, 2048 + h*64 + d] ----------------
__global__ __launch_bounds__(256) void k_vt(const u16* __restrict__ qkv,
                                            u16* __restrict__ vt) {
    __shared__ u16 tile[64][66];
    const int bh = blockIdx.y;
    const int b = bh >> 4, h = bh & 15;
    const int n0 = blockIdx.x * 64;
    const int tid = threadIdx.x;
#pragma unroll
    for (int it = 0; it < 16; ++it) {
        int idx = it * 256 + tid;
        int r = idx >> 6, c = idx & 63;
        tile[r][c] = qkv[(size_t)(b * 2048 + n0 + r) * 3072 + 2048 + h * 64 + c];
    }
    __syncthreads();
#pragma unroll
    for (int it = 0; it < 16; ++it) {
        int idx = it * 256 + tid;
        int d = idx >> 6, c = idx & 63;
        vt[(size_t)(bh * 64 + d) * 2048 + n0 + c] = tile[c][d];
    }
}

// ---------------- windowed attention, paired q-tiles ----------------
// Block = q-tiles (p, 31-p) of one (b,h): uniform 35 tile-computations/block.
// 4 waves x 16 q-rows each. No running max: Q pre-scaled by 0.125*log2e in the
// qkv GEMM, p = exp2(S'), unnormalized accumulation, single divide at the end.
// S^T = mfma(K, Q): D row = kv, D col = q (lane&15) -> q-sum is lane-local.
__device__ __forceinline__ void attn_leg(const u16* __restrict__ Ksb,
                                         const u16* __restrict__ Vsb,
                                         u16* __restrict__ Plw,
                                         int lr, int lg, bf16x8 q0, bf16x8 q1,
                                         f32x4 (&o)[4], float& ls,
                                         int thr, bool domask) {
    f32x4 st[4];
#pragma unroll
    for (int f = 0; f < 4; ++f) st[f] = (f32x4){0.f, 0.f, 0.f, 0.f};
#pragma unroll
    for (int s = 0; s < 2; ++s) {
        const bf16x8 qf = s ? q1 : q0;
#pragma unroll
        for (int f = 0; f < 4; ++f) {
            const int row = f * 16 + lr;
            const int sw = ((s * 4 + lg) ^ (row & 7)) * 8;
            bf16x8 kf = *(const bf16x8*)&Ksb[row * 64 + sw];
            st[f] = mfma16(kf, qf, st[f]);
        }
    }
    const int kbase = lg * 4;
#pragma unroll
    for (int f = 0; f < 4; ++f) {
        float pv[4];
#pragma unroll
        for (int r = 0; r < 4; ++r) {
            float sv = st[f][r];
            if (domask) sv = (f * 16 + kbase + r > thr) ? -1e30f : sv;
            pv[r] = exp2f(sv);
            ls += pv[r];
        }
        ushort4 pw;
        pw.x = f2bf(pv[0]); pw.y = f2bf(pv[1]); pw.z = f2bf(pv[2]); pw.w = f2bf(pv[3]);
        *(ushort4*)&Plw[lr * 80 + f * 16 + kbase] = pw;   // P[q][kv], stride 80 u16
    }
#pragma unroll
    for (int s = 0; s < 2; ++s) {
        const bf16x8 pf = *(const bf16x8*)&Plw[lr * 80 + s * 32 + lg * 8];
#pragma unroll
        for (int f = 0; f < 4; ++f) {
            const int row = f * 16 + lr;
            const int sw = ((s * 4 + lg) ^ (row & 7)) * 8;
            bf16x8 vf = *(const bf16x8*)&Vsb[row * 64 + sw];
            o[f] = mfma16(pf, vf, o[f]);
        }
    }
}

__global__ __launch_bounds__(256) void k_attn(const u16* __restrict__ qkv,
                                              const u16* __restrict__ vt,
                                              u16* __restrict__ ao) {
    __shared__ __align__(16) u16 Ks[2][64 * 64];
    __shared__ __align__(16) u16 Vs[2][64 * 64];
    __shared__ __align__(16) u16 Pl[4][16 * 80];
    const int p = blockIdx.x, bh = blockIdx.y, b = bh >> 4, h = bh & 15;
    const int tid = threadIdx.x, w = tid >> 6, l = tid & 63;
    const int lr = l & 15, lg = l >> 4;
    const int iA = p, iB = 31 - p;
    const int ntA = min(iA + 2, 32);   // CLAMP: lookahead tile must not pass N/64
    const int ntB = min(iB + 2, 32);

    const size_t qbA = (size_t)(b * 2048 + iA * 64 + w * 16 + lr) * 3072 + h * 64;
    const size_t qbB = (size_t)(b * 2048 + iB * 64 + w * 16 + lr) * 3072 + h * 64;
    const bf16x8 qA0 = *(const bf16x8*)&qkv[qbA + lg * 8];
    const bf16x8 qA1 = *(const bf16x8*)&qkv[qbA + 32 + lg * 8];
    const bf16x8 qB0 = *(const bf16x8*)&qkv[qbB + lg * 8];
    const bf16x8 qB1 = *(const bf16x8*)&qkv[qbB + 32 + lg * 8];

    f32x4 oA[4], oB[4];
#pragma unroll
    for (int f = 0; f < 4; ++f) {
        oA[f] = (f32x4){0.f, 0.f, 0.f, 0.f};
        oB[f] = (f32x4){0.f, 0.f, 0.f, 0.f};
    }
    float lsA = 0.f, lsB = 0.f;
    const int qlA = iA * 64 + w * 16 + lr;
    const int qlB = iB * 64 + w * 16 + lr;

    // stage tile t into buffer buf (K and V^T, XOR-swizzled via global source)
    auto STAGE = [&](int buf, int t) {
        const int j0 = t * 64;
#pragma unroll
        for (int it = 0; it < 2; ++it) {
            const int cbase = it * 256 + w * 64;
            const int c = cbase + l;
            const int row = c >> 3, slot = c & 7;
            const int ss = slot ^ (row & 7);
            gload16(&qkv[(size_t)(b * 2048 + j0 + row) * 3072 + 1024 + h * 64 + ss * 8],
                    &Ks[buf][cbase * 8]);
            gload16(&vt[(size_t)(bh * 64 + row) * 2048 + j0 + ss * 8], &Vs[buf][cbase * 8]);
        }
    };

    STAGE(0, 0);
    __syncthreads();
    for (int t = 0; t < ntB; ++t) {
        const int cur = t & 1;
        if (t + 1 < ntB) STAGE(cur ^ 1, t + 1);
        attn_leg(Ks[cur], Vs[cur], Pl[w], lr, lg, qB0, qB1, oB, lsB,
                 qlB + 63 - t * 64, t == ntB - 1);
        if (t < ntA)
            attn_leg(Ks[cur], Vs[cur], Pl[w], lr, lg, qA0, qA1, oA, lsA,
                     qlA + 63 - t * 64, t == ntA - 1);
        __syncthreads();
    }

    // epilogue: reduce row sums, normalize, write both q-tiles
    lsA += __shfl_xor(lsA, 16); lsA += __shfl_xor(lsA, 32);
    lsB += __shfl_xor(lsB, 16); lsB += __shfl_xor(lsB, 32);
    float liA[4], liB[4];
#pragma unroll
    for (int r = 0; r < 4; ++r) {
        liA[r] = 1.0f / __shfl(lsA, lg * 4 + r);
        liB[r] = 1.0f / __shfl(lsB, lg * 4 + r);
    }
#pragma unroll
    for (int f = 0; f < 4; ++f) {
#pragma unroll
        for (int r = 0; r < 4; ++r) {
            const int rowA = b * 2048 + iA * 64 + w * 16 + lg * 4 + r;
            const int rowB = b * 2048 + iB * 64 + w * 16 + lg * 4 + r;
            ao[(size_t)rowA * 1024 + h * 64 + f * 16 + lr] = f2bf(oA[f][r] * liA[r]);
            ao[(size_t)rowB * 1024 + h * 64 + f * 16 + lr] = f2bf(oB[f][r] * liB[r]);
        }
    }
}

extern "C" void kernel_launch(void* const* d_in, const int* in_sizes, int n_in,
                              void* d_out, int out_size, void* d_ws, size_t ws_size,
                              hipStream_t stream) {
    const float* x  = (const float*)d_in[0];
    const float* W1 = (const float*)d_in[1];
    const float* b1 = (const float*)d_in[2];
    const float* W2 = (const float*)d_in[3];
    const float* b2 = (const float*)d_in[4];
    const float* Wg = (const float*)d_in[5];
    const float* bg = (const float*)d_in[6];
    const float* Wo = (const float*)d_in[7];
    const float* bo = (const float*)d_in[8];
    float* out = (float*)d_out;

    char* ws = (char*)d_ws;
    const size_t MB = 1024 * 1024;
    u16* x_bf   = (u16*)(ws + 0);        // 8 MB
    u16* w1_bf  = (u16*)(ws + 8  * MB);  // 2 MB
    u16* w2_bf  = (u16*)(ws + 10 * MB);  // 2 MB
    u16* wg_bf  = (u16*)(ws + 12 * MB);  // 6 MB
    u16* wo_bf  = (u16*)(ws + 18 * MB);  // 2 MB
    u16* h1_bf  = (u16*)(ws + 20 * MB);  // 8 MB
    u16* h_bf   = (u16*)(ws + 28 * MB);  // 8 MB
    u16* qkv_bf = (u16*)(ws + 36 * MB);  // 24 MB
    u16* vt_bf  = (u16*)(ws + 60 * MB);  // 8 MB
    u16* ao_bf  = (u16*)(ws + 68 * MB);  // 8 MB (total 76 MB)

    k_cvt<<<4096, 256, 0, stream>>>(x,  x_bf,  1048576);
    k_cvt<<<1024, 256, 0, stream>>>(W1, w1_bf, 262144);
    k_cvt<<<1024, 256, 0, stream>>>(W2, w2_bf, 262144);
    k_cvt<<<3072, 256, 0, stream>>>(Wg, wg_bf, 786432);
    k_cvt<<<1024, 256, 0, stream>>>(Wo, wo_bf, 262144);

    k_gemm<true,  true ><<<dim3(32, 8),  256, 0, stream>>>(x_bf,  w1_bf, b1, h1_bf,  4096, 1024, 1024, 0);
    k_gemm<false, true ><<<dim3(32, 8),  256, 0, stream>>>(h1_bf, w2_bf, b2, h_bf,   4096, 1024, 1024, 0);
    k_gemm<false, true ><<<dim3(32, 24), 256, 0, stream>>>(h_bf,  wg_bf, bg, qkv_bf, 4096, 3072, 1024, 1024);

    k_vt  <<<dim3(32, 32), 256, 0, stream>>>(qkv_bf, vt_bf);
    k_attn<<<dim3(16, 32), 256, 0, stream>>>(qkv_bf, vt_bf, ao_bf);

    k_gemm<false, false><<<dim3(32, 8), 256, 0, stream>>>(ao_bf, wo_bf, bo, out, 4096, 1024, 1024, 0);
}

// Round 4
// 155.886 us; speedup vs baseline: 1.5561x; 1.2518x over previous
//
#include <hip/hip_runtime.h>

typedef unsigned short u16;
typedef unsigned int   u32;
typedef __bf16 bf16x8 __attribute__((ext_vector_type(8)));
typedef float  f32x4  __attribute__((ext_vector_type(4)));

__device__ __forceinline__ u16 f2bf(float f) {
    u32 u = __builtin_bit_cast(u32, f);
    u32 r = u + 0x7fffu + ((u >> 16) & 1u);   // RNE
    return (u16)(r >> 16);
}

__device__ __forceinline__ void gload16(const void* g, void* lds) {
    __builtin_amdgcn_global_load_lds(
        (const __attribute__((address_space(1))) u32*)g,
        (__attribute__((address_space(3))) u32*)lds, 16, 0, 0);
}

__device__ __forceinline__ f32x4 mfma16(bf16x8 a, bf16x8 b, f32x4 c) {
    return __builtin_amdgcn_mfma_f32_16x16x32_bf16(a, b, c, 0, 0, 0);
}

// ---------------- fused fp32 -> bf16 convert of all 5 inputs ----------------
// region boundaries in float4 units (all 256-aligned -> block-uniform branch)
__global__ __launch_bounds__(256) void k_cvt5(const float* __restrict__ x,
                                              const float* __restrict__ W1,
                                              const float* __restrict__ W2,
                                              const float* __restrict__ Wg,
                                              const float* __restrict__ Wo,
                                              u16* __restrict__ xb, u16* __restrict__ w1b,
                                              u16* __restrict__ w2b, u16* __restrict__ wgb,
                                              u16* __restrict__ wob) {
    int i = blockIdx.x * 256 + threadIdx.x;
    const float* src; u16* dst; int off;
    if (i < 1048576)      { src = x;  dst = xb;  off = 0; }
    else if (i < 1310720) { src = W1; dst = w1b; off = 1048576; }
    else if (i < 1572864) { src = W2; dst = w2b; off = 1310720; }
    else if (i < 2359296) { src = Wg; dst = wgb; off = 1572864; }
    else                  { src = Wo; dst = wob; off = 2359296; }
    int j = i - off;
    float4 v = ((const float4*)src)[j];
    ushort4 o;
    o.x = f2bf(v.x); o.y = f2bf(v.y); o.z = f2bf(v.z); o.w = f2bf(v.w);
    ((ushort4*)dst)[j] = o;
}

// ---------------- NT GEMM: C[m,n] = sum_k A[m,k]*B[n,k] + bias[n] ----------------
// 128x128 tile, BK=64, 8 waves (2x4), wave tile 64x32 = 4x2 frags of 16x16x32.
// Double-buffered LDS, prefetch-ahead 2-phase: STAGE(t+1); COMPUTE(t); barrier.
// LDS XOR-swizzled (slot ^= row&7) via pre-swizzled global source (m173 pattern).
// Columns col < qcols get scaled by 0.125*log2(e) (pre-scale of attention Q).
template<bool SILU, bool OUT_BF16>
__global__ __launch_bounds__(512) void k_gemm(const u16* __restrict__ A,
                                              const u16* __restrict__ B,
                                              const float* __restrict__ bias,
                                              void* __restrict__ Cout,
                                              int M, int N, int K, int qcols) {
    __shared__ __align__(16) u16 As[2][128 * 64];
    __shared__ __align__(16) u16 Bs[2][128 * 64];
    const int tid = threadIdx.x;
    const int w = tid >> 6, l = tid & 63;
    const int wm = w >> 2, wn = w & 3;           // 2 x 4 wave grid
    const int lr = l & 15, lg = l >> 4;

    // bijective XCD swizzle (grids here are multiples of 8)
    const int nwg = gridDim.x * gridDim.y;
    const int hw = blockIdx.x + gridDim.x * blockIdx.y;
    const int wg = (hw & 7) * (nwg >> 3) + (hw >> 3);
    const int m0 = (wg % gridDim.x) * 128, n0 = (wg / gridDim.x) * 128;

    f32x4 acc[4][2];
#pragma unroll
    for (int i = 0; i < 4; ++i)
#pragma unroll
        for (int j = 0; j < 2; ++j) acc[i][j] = (f32x4){0.f, 0.f, 0.f, 0.f};

    // staging: 32 KB / 512 thr = 4 x 16B chunks each; waves 0-3 -> As, 4-7 -> Bs.
    // lane l writes LDS (row = g*8 + l/8, slot = l%8); source slot = (l%8)^((l/8)&7)
    const int srow = l >> 3;
    const int ss = (l & 7) ^ (srow & 7);
    auto STAGE = [&](int buf, int kt) {
#pragma unroll
        for (int i = 0; i < 4; ++i) {
            const int g = w * 4 + i;
            if (g < 16)
                gload16(&A[(size_t)(m0 + g * 8 + srow) * K + kt * 64 + ss * 8],
                        &As[buf][g * 512]);
            else
                gload16(&B[(size_t)(n0 + (g - 16) * 8 + srow) * K + kt * 64 + ss * 8],
                        &Bs[buf][(g - 16) * 512]);
        }
    };

    const int nkt = K >> 6;
    STAGE(0, 0);
    __syncthreads();
    for (int kt = 0; kt < nkt; ++kt) {
        const int cur = kt & 1;
        if (kt + 1 < nkt) STAGE(cur ^ 1, kt + 1);
#pragma unroll
        for (int s = 0; s < 2; ++s) {
            bf16x8 af[4], bq[2];
#pragma unroll
            for (int f = 0; f < 4; ++f) {
                const int r = wm * 64 + f * 16 + lr;
                af[f] = *(const bf16x8*)&As[cur][r * 64 + (((s * 4 + lg) ^ (r & 7)) * 8)];
            }
#pragma unroll
            for (int n = 0; n < 2; ++n) {
                const int r = wn * 32 + n * 16 + lr;
                bq[n] = *(const bf16x8*)&Bs[cur][r * 64 + (((s * 4 + lg) ^ (r & 7)) * 8)];
            }
#pragma unroll
            for (int mf = 0; mf < 4; ++mf)
#pragma unroll
                for (int nf = 0; nf < 2; ++nf)
                    acc[mf][nf] = mfma16(af[mf], bq[nf], acc[mf][nf]);
        }
        if (kt + 1 < nkt) __syncthreads();
    }

    // epilogue: D col = lane&15, row = (lane>>4)*4 + reg   [verified mapping]
#pragma unroll
    for (int nf = 0; nf < 2; ++nf) {
        const int col = n0 + wn * 32 + nf * 16 + lr;
        const float bv = bias[col];
        const float cs = (col < qcols) ? 0.18033688011112042f : 1.0f;
#pragma unroll
        for (int mf = 0; mf < 4; ++mf) {
#pragma unroll
            for (int r = 0; r < 4; ++r) {
                const int row = m0 + wm * 64 + mf * 16 + lg * 4 + r;
                float v = acc[mf][nf][r] + bv;
                if (SILU) v = v / (1.0f + __expf(-v));
                v *= cs;
                if (OUT_BF16) ((u16*)Cout)[(size_t)row * N + col] = f2bf(v);
                else          ((float*)Cout)[(size_t)row * N + col] = v;
            }
        }
    }
}

// ---------------- V transpose: vt[bh][d][n] = qkv[b, n, 2048 + h*64 + d] ----------------
__global__ __launch_bounds__(256) void k_vt(const u16* __restrict__ qkv,
                                            u16* __restrict__ vt) {
    __shared__ u16 tile[64][66];
    const int bh = blockIdx.y;
    const int b = bh >> 4, h = bh & 15;
    const int n0 = blockIdx.x * 64;
    const int tid = threadIdx.x;
#pragma unroll
    for (int it = 0; it < 16; ++it) {
        int idx = it * 256 + tid;
        int r = idx >> 6, c = idx & 63;
        tile[r][c] = qkv[(size_t)(b * 2048 + n0 + r) * 3072 + 2048 + h * 64 + c];
    }
    __syncthreads();
#pragma unroll
    for (int it = 0; it < 16; ++it) {
        int idx = it * 256 + tid;
        int d = idx >> 6, c = idx & 63;
        vt[(size_t)(bh * 64 + d) * 2048 + n0 + c] = tile[c][d];
    }
}

// ---------------- windowed attention, paired q-tiles ----------------
// Block = q-tiles (p, 31-p) of one (b,h): uniform 35 tile-computations/block.
// 4 waves x 16 q-rows each. No running max: Q pre-scaled by 0.125*log2e in the
// qkv GEMM, p = exp2(S'), unnormalized accumulation, single divide at the end.
// S^T = mfma(K, Q): D row = kv, D col = q (lane&15) -> q-sum is lane-local.
__device__ __forceinline__ void attn_leg(const u16* __restrict__ Ksb,
                                         const u16* __restrict__ Vsb,
                                         u16* __restrict__ Plw,
                                         int lr, int lg, bf16x8 q0, bf16x8 q1,
                                         f32x4 (&o)[4], float& ls,
                                         int thr, bool domask) {
    f32x4 st[4];
#pragma unroll
    for (int f = 0; f < 4; ++f) st[f] = (f32x4){0.f, 0.f, 0.f, 0.f};
#pragma unroll
    for (int s = 0; s < 2; ++s) {
        const bf16x8 qf = s ? q1 : q0;
#pragma unroll
        for (int f = 0; f < 4; ++f) {
            const int row = f * 16 + lr;
            const int sw = ((s * 4 + lg) ^ (row & 7)) * 8;
            bf16x8 kf = *(const bf16x8*)&Ksb[row * 64 + sw];
            st[f] = mfma16(kf, qf, st[f]);
        }
    }
    const int kbase = lg * 4;
#pragma unroll
    for (int f = 0; f < 4; ++f) {
        float pv[4];
#pragma unroll
        for (int r = 0; r < 4; ++r) {
            float sv = st[f][r];
            if (domask) sv = (f * 16 + kbase + r > thr) ? -1e30f : sv;
            pv[r] = exp2f(sv);
            ls += pv[r];
        }
        ushort4 pw;
        pw.x = f2bf(pv[0]); pw.y = f2bf(pv[1]); pw.z = f2bf(pv[2]); pw.w = f2bf(pv[3]);
        *(ushort4*)&Plw[lr * 80 + f * 16 + kbase] = pw;   // P[q][kv], stride 80 u16
    }
#pragma unroll
    for (int s = 0; s < 2; ++s) {
        const bf16x8 pf = *(const bf16x8*)&Plw[lr * 80 + s * 32 + lg * 8];
#pragma unroll
        for (int f = 0; f < 4; ++f) {
            const int row = f * 16 + lr;
            const int sw = ((s * 4 + lg) ^ (row & 7)) * 8;
            bf16x8 vf = *(const bf16x8*)&Vsb[row * 64 + sw];
            o[f] = mfma16(pf, vf, o[f]);
        }
    }
}

__global__ __launch_bounds__(256) void k_attn(const u16* __restrict__ qkv,
                                              const u16* __restrict__ vt,
                                              u16* __restrict__ ao) {
    __shared__ __align__(16) u16 Ks[2][64 * 64];
    __shared__ __align__(16) u16 Vs[2][64 * 64];
    __shared__ __align__(16) u16 Pl[4][16 * 80];
    // bijective XCD swizzle: cluster the 16 p-blocks x 4 heads per XCD (K/V ~2MB L2-resident)
    const int hw = blockIdx.x + 16 * blockIdx.y;        // nwg = 512
    const int logical = (hw & 7) * 64 + (hw >> 3);
    const int p = logical & 15, bh = logical >> 4;
    const int b = bh >> 4, h = bh & 15;
    const int tid = threadIdx.x, w = tid >> 6, l = tid & 63;
    const int lr = l & 15, lg = l >> 4;
    const int iA = p, iB = 31 - p;
    const int ntA = min(iA + 2, 32);   // CLAMP: lookahead tile must not pass N/64
    const int ntB = min(iB + 2, 32);

    const size_t qbA = (size_t)(b * 2048 + iA * 64 + w * 16 + lr) * 3072 + h * 64;
    const size_t qbB = (size_t)(b * 2048 + iB * 64 + w * 16 + lr) * 3072 + h * 64;
    const bf16x8 qA0 = *(const bf16x8*)&qkv[qbA + lg * 8];
    const bf16x8 qA1 = *(const bf16x8*)&qkv[qbA + 32 + lg * 8];
    const bf16x8 qB0 = *(const bf16x8*)&qkv[qbB + lg * 8];
    const bf16x8 qB1 = *(const bf16x8*)&qkv[qbB + 32 + lg * 8];

    f32x4 oA[4], oB[4];
#pragma unroll
    for (int f = 0; f < 4; ++f) {
        oA[f] = (f32x4){0.f, 0.f, 0.f, 0.f};
        oB[f] = (f32x4){0.f, 0.f, 0.f, 0.f};
    }
    float lsA = 0.f, lsB = 0.f;
    const int qlA = iA * 64 + w * 16 + lr;
    const int qlB = iB * 64 + w * 16 + lr;

    // stage tile t into buffer buf (K and V^T, XOR-swizzled via global source)
    auto STAGE = [&](int buf, int t) {
        const int j0 = t * 64;
#pragma unroll
        for (int it = 0; it < 2; ++it) {
            const int cbase = it * 256 + w * 64;
            const int c = cbase + l;
            const int row = c >> 3, slot = c & 7;
            const int ss = slot ^ (row & 7);
            gload16(&qkv[(size_t)(b * 2048 + j0 + row) * 3072 + 1024 + h * 64 + ss * 8],
                    &Ks[buf][cbase * 8]);
            gload16(&vt[(size_t)(bh * 64 + row) * 2048 + j0 + ss * 8], &Vs[buf][cbase * 8]);
        }
    };

    STAGE(0, 0);
    __syncthreads();
    for (int t = 0; t < ntB; ++t) {
        const int cur = t & 1;
        if (t + 1 < ntB) STAGE(cur ^ 1, t + 1);
        attn_leg(Ks[cur], Vs[cur], Pl[w], lr, lg, qB0, qB1, oB, lsB,
                 qlB + 63 - t * 64, t == ntB - 1);
        if (t < ntA)
            attn_leg(Ks[cur], Vs[cur], Pl[w], lr, lg, qA0, qA1, oA, lsA,
                     qlA + 63 - t * 64, t == ntA - 1);
        __syncthreads();
    }

    // epilogue: reduce row sums, normalize, write both q-tiles
    lsA += __shfl_xor(lsA, 16); lsA += __shfl_xor(lsA, 32);
    lsB += __shfl_xor(lsB, 16); lsB += __shfl_xor(lsB, 32);
    float liA[4], liB[4];
#pragma unroll
    for (int r = 0; r < 4; ++r) {
        liA[r] = 1.0f / __shfl(lsA, lg * 4 + r);
        liB[r] = 1.0f / __shfl(lsB, lg * 4 + r);
    }
#pragma unroll
    for (int f = 0; f < 4; ++f) {
#pragma unroll
        for (int r = 0; r < 4; ++r) {
            const int rowA = b * 2048 + iA * 64 + w * 16 + lg * 4 + r;
            const int rowB = b * 2048 + iB * 64 + w * 16 + lg * 4 + r;
            ao[(size_t)rowA * 1024 + h * 64 + f * 16 + lr] = f2bf(oA[f][r] * liA[r]);
            ao[(size_t)rowB * 1024 + h * 64 + f * 16 + lr] = f2bf(oB[f][r] * liB[r]);
        }
    }
}

extern "C" void kernel_launch(void* const* d_in, const int* in_sizes, int n_in,
                              void* d_out, int out_size, void* d_ws, size_t ws_size,
                              hipStream_t stream) {
    const float* x  = (const float*)d_in[0];
    const float* W1 = (const float*)d_in[1];
    const float* b1 = (const float*)d_in[2];
    const float* W2 = (const float*)d_in[3];
    const float* b2 = (const float*)d_in[4];
    const float* Wg = (const float*)d_in[5];
    const float* bg = (const float*)d_in[6];
    const float* Wo = (const float*)d_in[7];
    const float* bo = (const float*)d_in[8];
    float* out = (float*)d_out;

    char* ws = (char*)d_ws;
    const size_t MB = 1024 * 1024;
    u16* x_bf   = (u16*)(ws + 0);        // 8 MB
    u16* w1_bf  = (u16*)(ws + 8  * MB);  // 2 MB
    u16* w2_bf  = (u16*)(ws + 10 * MB);  // 2 MB
    u16* wg_bf  = (u16*)(ws + 12 * MB);  // 6 MB
    u16* wo_bf  = (u16*)(ws + 18 * MB);  // 2 MB
    u16* h1_bf  = (u16*)(ws + 20 * MB);  // 8 MB
    u16* h_bf   = (u16*)(ws + 28 * MB);  // 8 MB
    u16* qkv_bf = (u16*)(ws + 36 * MB);  // 24 MB
    u16* vt_bf  = (u16*)(ws + 60 * MB);  // 8 MB
    u16* ao_bf  = (u16*)(ws + 68 * MB);  // 8 MB (total 76 MB)

    k_cvt5<<<10240, 256, 0, stream>>>(x, W1, W2, Wg, Wo,
                                      x_bf, w1_bf, w2_bf, wg_bf, wo_bf);

    k_gemm<true,  true ><<<dim3(32, 8),  512, 0, stream>>>(x_bf,  w1_bf, b1, h1_bf,  4096, 1024, 1024, 0);
    k_gemm<false, true ><<<dim3(32, 8),  512, 0, stream>>>(h1_bf, w2_bf, b2, h_bf,   4096, 1024, 1024, 0);
    k_gemm<false, true ><<<dim3(32, 24), 512, 0, stream>>>(h_bf,  wg_bf, bg, qkv_bf, 4096, 3072, 1024, 1024);

    k_vt  <<<dim3(32, 32), 256, 0, stream>>>(qkv_bf, vt_bf);
    k_attn<<<dim3(16, 32), 256, 0, stream>>>(qkv_bf, vt_bf, ao_bf);

    k_gemm<false, false><<<dim3(32, 8), 512, 0, stream>>>(ao_bf, wo_bf, bo, out, 4096, 1024, 1024, 0);
}